// Round 21
// baseline (102.273 us; speedup 1.0000x reference)
//
#include <hip/hip_runtime.h>
#include <hip/hip_bf16.h>
#include <hip/hip_fp16.h>
#include <cstdint>
#include <cstddef>

typedef __bf16 bf16;
typedef __bf16 bf16x8 __attribute__((ext_vector_type(8)));
typedef float f32x4 __attribute__((ext_vector_type(4)));

static constexpr int NB = 4;       // batch
static constexpr int S  = 8192;
static constexpr int D  = 512;
static constexpr int H  = 512;
static constexpr int M  = NB * S;  // 32768
static constexpr int CH = 64;      // scan chunk length
static constexpr int NC = S / CH;  // 128 chunks per sequence

#define BM 128
#define BN 128
#define BK 64
#define KSTEPS 8

// async global->LDS, 16B per lane. LDS dest is wave-uniform base + lane*16.
__device__ __forceinline__ void ld_lds16(void* lds, const void* g) {
  __builtin_amdgcn_global_load_lds(
      (const __attribute__((address_space(1))) uint32_t*)g,
      (__attribute__((address_space(3))) uint32_t*)lds, 16, 0, 0);
}

// Weights only: f32 -> bf16 with XOR-swizzled 16B-block placement within each
// row (dst block = blk ^ (row&7)) so linear global_load_lds staging yields a
// conflict-free LDS layout.
__global__ void cvt_w(const float* __restrict__ Wz, bf16* __restrict__ Wzb,
                      const float* __restrict__ Wh, bf16* __restrict__ Whb) {
  int idx = blockIdx.x * blockDim.x + threadIdx.x;  // one 8-elem block each
  const int per = H * (D / 8);                      // 32768 per weight
  const float* src; bf16* dst;
  if (idx < per) { src = Wz; dst = Wzb; }
  else           { src = Wh; dst = Whb; idx -= per; }
  const int row = idx >> 6;        // D/8 = 64 blocks per row
  const int blk = idx & 63;
  const float* s = src + (size_t)row * D + blk * 8;
  const float4 f0 = *(const float4*)s;
  const float4 f1 = *(const float4*)(s + 4);
  bf16x8 o;
  o[0] = (bf16)f0.x; o[1] = (bf16)f0.y; o[2] = (bf16)f0.z; o[3] = (bf16)f0.w;
  o[4] = (bf16)f1.x; o[5] = (bf16)f1.y; o[6] = (bf16)f1.z; o[7] = (bf16)f1.w;
  const int dblk = blk ^ (row & 7);
  *(bf16x8*)(dst + (size_t)row * D + dblk * 8) = o;
}

// Fused dual-GEMM + gates + per-chunk affine summaries.
// R18 skeleton + COUNTED-VMCNT barriers (T4) + W-dbuf (80 KB = 2 blocks/CU):
//   #1 (As write->read): lgkmcnt(0) only — W(ks+1) stage keeps flying.
//   #2 (post-compute):   vmcnt(8) — forces W(ks+1) [8 oldest ops, issued a
//       full phase earlier]; X(ks+1) prefetch flies across the barrier.
// asm volatile "memory" fences pin vmem issue order [W older, X younger],
// so vmcnt(8) provably forces the W ops. WAR separated by #2 (R19 proof).
__global__ __launch_bounds__(256, 2)
void gemm_gates(const float* __restrict__ Xf,
                const bf16* __restrict__ Wzb,
                const bf16* __restrict__ Whb,
                const float* __restrict__ bz,
                const float* __restrict__ bh,
                __half2* __restrict__ AB,
                float* __restrict__ cA,
                float* __restrict__ cB) {
  __shared__ __attribute__((aligned(16))) bf16 As[BM * BK];
  __shared__ __attribute__((aligned(16))) bf16 Zs0[BN * BK];
  __shared__ __attribute__((aligned(16))) bf16 Zs1[BN * BK];
  __shared__ __attribute__((aligned(16))) bf16 Hs0[BN * BK];
  __shared__ __attribute__((aligned(16))) bf16 Hs1[BN * BK];

  // XCD-aware swizzle. Grid = 1024, 8 XCDs, chunk 128 (bijective). Each XCD
  // owns 32 consecutive mt (all 4 nt each): X-panels + W stay in its L2.
  const int bid = blockIdx.x;
  const int swz = (bid & 7) * 128 + (bid >> 3);
  const int mt = swz >> 2;          // n-tile fastest within an XCD chunk
  const int nt = swz & 3;
  const int m0 = mt * BM;
  const int n0 = nt * BN;
  const int tid = threadIdx.x;
  const int wave = tid >> 6;
  const int lane = tid & 63;
  const int wr = wave >> 1;   // 2x2 wave grid, each wave owns 64x64
  const int wc = wave & 1;
  const int lr = lane & 15;   // row (A) / col (B) within 16x16 frag
  const int lk = lane >> 4;   // k-octet group
  const int xk = (lr & 7) << 3;  // fragment-read XOR (elements)

  float4 xr[4][2];            // X staging registers (one K-step in flight)

  f32x4 accz[4][4], acch[4][4];
  const f32x4 vzero = {0.f, 0.f, 0.f, 0.f};
#pragma unroll
  for (int i = 0; i < 4; ++i)
#pragma unroll
    for (int j = 0; j < 4; ++j) { accz[i][j] = vzero; acch[i][j] = vzero; }

  auto loadX = [&](int ks) {
#pragma unroll
    for (int it = 0; it < 4; ++it) {
      const int idx = it * 256 + tid;
      const int row = idx >> 3;
      const int grp = idx & 7;
      const float* gp = Xf + (size_t)(m0 + row) * D + ks * BK + grp * 8;
      xr[it][0] = *(const float4*)gp;
      xr[it][1] = *(const float4*)(gp + 4);
    }
  };
  auto writeX = [&]() {
#pragma unroll
    for (int it = 0; it < 4; ++it) {
      const int idx = it * 256 + tid;
      const int row = idx >> 3;
      const int grp = idx & 7;
      bf16x8 o;
      o[0] = (bf16)xr[it][0].x; o[1] = (bf16)xr[it][0].y;
      o[2] = (bf16)xr[it][0].z; o[3] = (bf16)xr[it][0].w;
      o[4] = (bf16)xr[it][1].x; o[5] = (bf16)xr[it][1].y;
      o[6] = (bf16)xr[it][1].z; o[7] = (bf16)xr[it][1].w;
      *(bf16x8*)&As[row * BK + ((grp ^ (row & 7)) << 3)] = o;
    }
  };
  auto stageW = [&](int ks, bf16* Zd, bf16* Hd) {
#pragma unroll
    for (int it = 0; it < 4; ++it) {
      const int fb = it * 256 + wave * 64;  // wave-uniform 16B-block base
      const int f  = fb + lane;
      const int row = f >> 3;
      const int kc  = f & 7;
      const size_t gk = (size_t)ks * BK + kc * 8;
      ld_lds16(&Zd[(size_t)fb * 8], Wzb + (size_t)(n0 + row) * D + gk);
      ld_lds16(&Hd[(size_t)fb * 8], Whb + (size_t)(n0 + row) * D + gk);
    }
  };
  auto compute = [&](const bf16* Zc, const bf16* Hc) {
#pragma unroll
    for (int kk = 0; kk < 2; ++kk) {
      bf16x8 af[4], zf[4], hf[4];
      const int col = (kk * 32 + lk * 8) ^ xk;  // undo staging swizzle
#pragma unroll
      for (int m = 0; m < 4; ++m)
        af[m] = *(const bf16x8*)&As[(wr * 64 + m * 16 + lr) * BK + col];
#pragma unroll
      for (int n = 0; n < 4; ++n) {
        const int c = (wc * 64 + n * 16 + lr) * BK + col;
        zf[n] = *(const bf16x8*)&Zc[c];
        hf[n] = *(const bf16x8*)&Hc[c];
      }
#pragma unroll
      for (int m = 0; m < 4; ++m)
#pragma unroll
        for (int n = 0; n < 4; ++n) {
          accz[m][n] = __builtin_amdgcn_mfma_f32_16x16x32_bf16(af[m], zf[n], accz[m][n], 0, 0, 0);
          acch[m][n] = __builtin_amdgcn_mfma_f32_16x16x32_bf16(af[m], hf[n], acch[m][n], 0, 0, 0);
        }
    }
  };

  // prologue: X(0) regs + W(0) buf0; single full drain (forces X0 AND W0)
  loadX(0);
  stageW(0, Zs0, Hs0);
  asm volatile("s_waitcnt vmcnt(0)" ::: "memory");

#pragma unroll
  for (int ks = 0; ks < KSTEPS; ++ks) {
    const bf16* Zp = (ks & 1) ? Zs1 : Zs0;
    const bf16* Hp = (ks & 1) ? Hs1 : Hs0;
    bf16* Zq = (ks & 1) ? Zs0 : Zs1;
    bf16* Hq = (ks & 1) ? Hs0 : Hs1;
    if (ks < KSTEPS - 1) stageW(ks + 1, Zq, Hq);  // 8 vmem, fly across #1
    writeX();               // As <- xr = X(ks); ds_writes (lgkm)
    // #1: As visible to all waves. NO vmcnt drain — W(ks+1) keeps flying.
    asm volatile("s_waitcnt lgkmcnt(0)" ::: "memory");
    __builtin_amdgcn_s_barrier();
    if (ks < KSTEPS - 1) loadX(ks + 1);           // 8 vmem, fly across #2
    compute(Zp, Hp);        // reads As(ks) + W(ks) (forced at prev #2)
    if (ks < KSTEPS - 1) {
      // #2: force the 8 oldest vmem ops (= W(ks+1), issued a phase ago);
      // X(ks+1) [8 youngest] flies across into next iteration's writeX.
      asm volatile("s_waitcnt vmcnt(8) lgkmcnt(0)" ::: "memory");
      __builtin_amdgcn_s_barrier();
    }
  }

  // epilogue. C/D layout: col = lane&15, row = (lane>>4)*4 + reg.
  // m-outer/n-inner: full 256B row segments per m iteration (write locality).
  const int cg = (m0 >> 6) + wr;          // global chunk = b*NC + c
  float bzv[4], bhv[4], At[4], Bt[4];
#pragma unroll
  for (int n = 0; n < 4; ++n) {
    const int gn = n0 + wc * 64 + n * 16 + lr;
    bzv[n] = bz[gn];
    bhv[n] = bh[gn];
    At[n] = 1.f;
    Bt[n] = 0.f;
  }
#pragma unroll
  for (int m = 0; m < 4; ++m) {
#pragma unroll
    for (int n = 0; n < 4; ++n) {
      const int gn = n0 + wc * 64 + n * 16 + lr;
      float Aseg = 1.f, Bseg = 0.f;       // lane-local 4-row segment
#pragma unroll
      for (int j = 0; j < 4; ++j) {
        const int gm = m0 + wr * 64 + m * 16 + lk * 4 + j;
        const float vz = accz[m][n][j] + bzv[n];
        const float vh = acch[m][n][j] + bhv[n];
        const float ez = __expf(-vz);
        const float z = __builtin_amdgcn_rcpf(1.f + ez);
        const float e = __expf(-2.f * fabsf(vh));
        float th = (1.f - e) * __builtin_amdgcn_rcpf(1.f + e);
        th = (vh < 0.f) ? -th : th;
        float a = 1.f - z;
        a = fminf(fmaxf(a, 1e-8f), 1.f - 1e-8f);
        const float bb = z * th;
        __half2 pk;
        pk.x = __float2half_rn(a);
        pk.y = __float2half_rn(bb);
        AB[(size_t)gm * H + gn] = pk;
        Aseg = a * Aseg;
        Bseg = a * Bseg + bb;
      }
      // ordered tree over the 4 lane-groups (lk): comb(first,second)
      float pa = __shfl_xor(Aseg, 16);
      float pb = __shfl_xor(Bseg, 16);
      if (lane & 16) { Bseg = Aseg * pb + Bseg; Aseg = Aseg * pa; }
      else           { Bseg = pa * Bseg + pb;   Aseg = pa * Aseg; }
      pa = __shfl_xor(Aseg, 32);
      pb = __shfl_xor(Bseg, 32);
      if (lane & 32) { Bseg = Aseg * pb + Bseg; Aseg = Aseg * pa; }
      else           { Bseg = pa * Bseg + pb;   Aseg = pa * Aseg; }
      // compose this 16-row m-block into the chunk total for column n
      Bt[n] = Aseg * Bt[n] + Bseg;
      At[n] = Aseg * At[n];
    }
  }
  if (lk == 0) {
#pragma unroll
    for (int n = 0; n < 4; ++n) {
      const int gn = n0 + wc * 64 + n * 16 + lr;
      const size_t so = (size_t)cg * H + gn;
      cA[so] = At[n];
      cB[so] = Bt[n];
    }
  }
}

// Wave-parallel exclusive scan over chunk summaries: one wave per (b,h),
// Hillis-Steele affine scan over 2 segments of 64 chunks.
__global__ __launch_bounds__(256)
void scan_summary(const float* __restrict__ cA,
                  const float* __restrict__ cB,
                  float* __restrict__ pref) {
  const int w = blockIdx.x * 4 + (threadIdx.x >> 6);  // b*H + h
  const int lane = threadIdx.x & 63;
  const int b = w >> 9, h = w & (H - 1);
  float hin = 0.f;
#pragma unroll
  for (int seg = 0; seg < 2; ++seg) {
    const int c = seg * 64 + lane;
    const size_t so = ((size_t)b * NC + c) * H + h;
    float A = cA[so], Bv = cB[so];
#pragma unroll
    for (int d = 1; d < 64; d <<= 1) {
      const float pa = __shfl_up(A, d);
      const float pb = __shfl_up(Bv, d);
      if (lane >= d) { Bv = A * pb + Bv; A = A * pa; }
    }
    float eA = __shfl_up(A, 1);
    float eB = __shfl_up(Bv, 1);
    if (lane == 0) { eA = 1.f; eB = 0.f; }
    pref[so] = eA * hin + eB;
    const float tA = __shfl(A, 63);
    const float tB = __shfl(Bv, 63);
    hin = tA * hin + tB;
  }
}

// Apply: local scan with chunk prefix; reads packed (a,b), writes f32 h.
__global__ __launch_bounds__(512)
void scan_apply(const __half2* __restrict__ AB, float* __restrict__ out,
                const float* __restrict__ pref) {
  const int blk = blockIdx.x;
  const int b = blk / NC, c = blk % NC;
  const int h = threadIdx.x;
  const size_t base = ((size_t)b * S + (size_t)c * CH) * H + h;
  float hcur = pref[((size_t)b * NC + c) * H + h];
#pragma unroll 4
  for (int t = 0; t < CH; ++t) {
    const size_t off = base + (size_t)t * H;
    const float2 f = __half22float2(AB[off]);
    hcur = f.x * hcur + f.y;
    out[off] = hcur;
  }
}

extern "C" void kernel_launch(void* const* d_in, const int* in_sizes, int n_in,
                              void* d_out, int out_size, void* d_ws, size_t ws_size,
                              hipStream_t stream) {
  const float* x  = (const float*)d_in[0];
  const float* Wz = (const float*)d_in[1];
  const float* bz = (const float*)d_in[2];
  const float* Wh = (const float*)d_in[3];
  const float* bh = (const float*)d_in[4];
  float* out = (float*)d_out;

  char* ws = (char*)d_ws;
  __half2* AB = (__half2*)ws;                      // M*H half2 = 64 MB
  bf16*  Wzb  = (bf16*)(ws + (size_t)67108864);    // H*D bf16  = 0.5 MB
  bf16*  Whb  = (bf16*)(ws + (size_t)67633152);    // H*D bf16  = 0.5 MB
  float* cA   = (float*)(ws + (size_t)68157440);   // NB*NC*H   = 1 MB
  float* cB   = (float*)(ws + (size_t)69206016);   // 1 MB
  float* pref = (float*)(ws + (size_t)70254592);   // 1 MB

  cvt_w<<<2 * H * (D / 8) / 256, 256, 0, stream>>>(Wz, Wzb, Wh, Whb);
  gemm_gates<<<(M / BM) * (H / BN), 256, 0, stream>>>(x, Wzb, Whb, bz, bh,
                                                      AB, cA, cB);
  scan_summary<<<NB * H / 4, 256, 0, stream>>>(cA, cB, pref);
  scan_apply<<<NB * NC, H, 0, stream>>>(AB, out, pref);
}

// Round 22
// 83.164 us; speedup vs baseline: 1.2298x; 1.2298x over previous
//
#include <hip/hip_runtime.h>
#include <hip/hip_bf16.h>
#include <hip/hip_fp16.h>
#include <cstdint>
#include <cstddef>

typedef __bf16 bf16;
typedef __bf16 bf16x8 __attribute__((ext_vector_type(8)));
typedef float f32x4 __attribute__((ext_vector_type(4)));

static constexpr int NB = 4;       // batch
static constexpr int S  = 8192;
static constexpr int D  = 512;
static constexpr int H  = 512;
static constexpr int M  = NB * S;  // 32768
static constexpr int CH = 64;      // scan chunk length
static constexpr int NC = S / CH;  // 128 chunks per sequence

#define BM 128
#define BN 128
#define BK 64

// async global->LDS, 16B per lane. LDS dest is wave-uniform base + lane*16.
__device__ __forceinline__ void ld_lds16(void* lds, const void* g) {
  __builtin_amdgcn_global_load_lds(
      (const __attribute__((address_space(1))) uint32_t*)g,
      (__attribute__((address_space(3))) uint32_t*)lds, 16, 0, 0);
}

// Weights only: f32 -> bf16 with XOR-swizzled 16B-block placement within each
// row (dst block = blk ^ (row&7)) so linear global_load_lds staging yields a
// conflict-free LDS layout.
__global__ void cvt_w(const float* __restrict__ Wz, bf16* __restrict__ Wzb,
                      const float* __restrict__ Wh, bf16* __restrict__ Whb) {
  int idx = blockIdx.x * blockDim.x + threadIdx.x;  // one 8-elem block each
  const int per = H * (D / 8);                      // 32768 per weight
  const float* src; bf16* dst;
  if (idx < per) { src = Wz; dst = Wzb; }
  else           { src = Wh; dst = Whb; idx -= per; }
  const int row = idx >> 6;        // D/8 = 64 blocks per row
  const int blk = idx & 63;
  const float* s = src + (size_t)row * D + blk * 8;
  const float4 f0 = *(const float4*)s;
  const float4 f1 = *(const float4*)(s + 4);
  bf16x8 o;
  o[0] = (bf16)f0.x; o[1] = (bf16)f0.y; o[2] = (bf16)f0.z; o[3] = (bf16)f0.w;
  o[4] = (bf16)f1.x; o[5] = (bf16)f1.y; o[6] = (bf16)f1.z; o[7] = (bf16)f1.w;
  const int dblk = blk ^ (row & 7);
  *(bf16x8*)(dst + (size_t)row * D + dblk * 8) = o;
}

// Fused dual-GEMM + gates + per-chunk affine summaries (R12/R16 structure —
// best of 10 structural experiments, thrice-confirmed 83.4-83.7 us).
// X: reg-staged from f32 (fused cvt), loads issued one K-step ahead.
// W: global_load_lds issued FIRST in the iteration so writeX's counted
// vmcnt wait + cvt/ds_write work covers part of the W latency.
// Output: packed half2 (a, b) via regular stores (L2 coalesces partial
// lines; L3 keeps the stream for scan_apply — nt-stores hurt, R15).
// Closed axes: 3 blocks/CU (R7: L2 thrash), no-LDS (R5: latency-bound),
// W-dbuf 2-barrier (R9), BN=64 (R10), W-resident 1-wave (R11), A-direct
// (R13), nt-stores (R15), 8-wave 256-tile (R17: VGPR spill), 1-barrier
// full-dbuf (R19: __syncthreads drains vmcnt(0) incl. next-tile stage),
// counted-vmcnt graft (R21: T4 needs full 8-phase interleave — regressed,
// write-amp 2x; consistent with learn_hip m218/m248 regime-gate).
__global__ __launch_bounds__(256, 2)
void gemm_gates(const float* __restrict__ Xf,
                const bf16* __restrict__ Wzb,
                const bf16* __restrict__ Whb,
                const float* __restrict__ bz,
                const float* __restrict__ bh,
                __half2* __restrict__ AB,
                float* __restrict__ cA,
                float* __restrict__ cB) {
  __shared__ __attribute__((aligned(16))) bf16 As[BM * BK];
  __shared__ __attribute__((aligned(16))) bf16 Zs[BN * BK];
  __shared__ __attribute__((aligned(16))) bf16 Hs[BN * BK];

  // XCD-aware swizzle. Grid = 1024, 8 XCDs, chunk 128 (bijective). Each XCD
  // owns 32 consecutive mt (all 4 nt each): A-panels + W stay in its L2.
  const int bid = blockIdx.x;
  const int swz = (bid & 7) * 128 + (bid >> 3);
  const int mt = swz >> 2;          // n-tile fastest within an XCD chunk
  const int nt = swz & 3;
  const int m0 = mt * BM;
  const int n0 = nt * BN;
  const int tid = threadIdx.x;
  const int wave = tid >> 6;
  const int lane = tid & 63;
  const int wr = wave >> 1;   // 2x2 wave grid, each wave owns 64x64
  const int wc = wave & 1;
  const int lr = lane & 15;   // row (A) / col (B) within 16x16 frag
  const int lk = lane >> 4;   // k-octet group
  const int xk = (lr & 7) << 3;  // fragment-read XOR (elements)

  float4 xr[4][2];            // X staging registers (one K-step in flight)

  f32x4 accz[4][4], acch[4][4];
  const f32x4 vzero = {0.f, 0.f, 0.f, 0.f};
#pragma unroll
  for (int i = 0; i < 4; ++i)
#pragma unroll
    for (int j = 0; j < 4; ++j) { accz[i][j] = vzero; acch[i][j] = vzero; }

  auto loadX = [&](int ks) {
#pragma unroll
    for (int it = 0; it < 4; ++it) {
      const int idx = it * 256 + tid;
      const int row = idx >> 3;
      const int grp = idx & 7;
      const float* gp = Xf + (size_t)(m0 + row) * D + ks * BK + grp * 8;
      xr[it][0] = *(const float4*)gp;
      xr[it][1] = *(const float4*)(gp + 4);
    }
  };
  auto writeX = [&]() {
#pragma unroll
    for (int it = 0; it < 4; ++it) {
      const int idx = it * 256 + tid;
      const int row = idx >> 3;
      const int grp = idx & 7;
      bf16x8 o;
      o[0] = (bf16)xr[it][0].x; o[1] = (bf16)xr[it][0].y;
      o[2] = (bf16)xr[it][0].z; o[3] = (bf16)xr[it][0].w;
      o[4] = (bf16)xr[it][1].x; o[5] = (bf16)xr[it][1].y;
      o[6] = (bf16)xr[it][1].z; o[7] = (bf16)xr[it][1].w;
      *(bf16x8*)&As[row * BK + ((grp ^ (row & 7)) << 3)] = o;
    }
  };
  auto stageW = [&](int ks) {
#pragma unroll
    for (int it = 0; it < 4; ++it) {
      const int fb = it * 256 + wave * 64;  // wave-uniform 16B-block base
      const int f  = fb + lane;
      const int row = f >> 3;
      const int kc  = f & 7;
      const size_t gk = (size_t)ks * BK + kc * 8;
      ld_lds16(&Zs[(size_t)fb * 8], Wzb + (size_t)(n0 + row) * D + gk);
      ld_lds16(&Hs[(size_t)fb * 8], Whb + (size_t)(n0 + row) * D + gk);
    }
  };
  auto compute = [&]() {
#pragma unroll
    for (int kk = 0; kk < 2; ++kk) {
      bf16x8 af[4], zf[4], hf[4];
      const int col = (kk * 32 + lk * 8) ^ xk;  // undo staging swizzle
#pragma unroll
      for (int m = 0; m < 4; ++m)
        af[m] = *(const bf16x8*)&As[(wr * 64 + m * 16 + lr) * BK + col];
#pragma unroll
      for (int n = 0; n < 4; ++n) {
        const int c = (wc * 64 + n * 16 + lr) * BK + col;
        zf[n] = *(const bf16x8*)&Zs[c];
        hf[n] = *(const bf16x8*)&Hs[c];
      }
#pragma unroll
      for (int m = 0; m < 4; ++m)
#pragma unroll
        for (int n = 0; n < 4; ++n) {
          accz[m][n] = __builtin_amdgcn_mfma_f32_16x16x32_bf16(af[m], zf[n], accz[m][n], 0, 0, 0);
          acch[m][n] = __builtin_amdgcn_mfma_f32_16x16x32_bf16(af[m], hf[n], acch[m][n], 0, 0, 0);
        }
    }
  };

  // prologue: X(0) to regs
  loadX(0);

  for (int ks = 0; ks < D / BK; ++ks) {
    stageW(ks);               // issue W loads FIRST: they fly under writeX
    writeX();                 // counted vmcnt wait on xr only (older ops)
    __syncthreads();          // #1: drain (W residual partially covered)
    if (ks < D / BK - 1) loadX(ks + 1);  // flies under the MFMA phase
    compute();
    __syncthreads();          // #2: WAR-safe; drain covered by MFMA phase
  }

  // epilogue. C/D layout: col = lane&15, row = (lane>>4)*4 + reg.
  // m-outer/n-inner: full 256B row segments per m iteration (write locality).
  const int cg = (m0 >> 6) + wr;          // global chunk = b*NC + c
  float bzv[4], bhv[4], At[4], Bt[4];
#pragma unroll
  for (int n = 0; n < 4; ++n) {
    const int gn = n0 + wc * 64 + n * 16 + lr;
    bzv[n] = bz[gn];
    bhv[n] = bh[gn];
    At[n] = 1.f;
    Bt[n] = 0.f;
  }
#pragma unroll
  for (int m = 0; m < 4; ++m) {
#pragma unroll
    for (int n = 0; n < 4; ++n) {
      const int gn = n0 + wc * 64 + n * 16 + lr;
      float Aseg = 1.f, Bseg = 0.f;       // lane-local 4-row segment
#pragma unroll
      for (int j = 0; j < 4; ++j) {
        const int gm = m0 + wr * 64 + m * 16 + lk * 4 + j;
        const float vz = accz[m][n][j] + bzv[n];
        const float vh = acch[m][n][j] + bhv[n];
        const float ez = __expf(-vz);
        const float z = __builtin_amdgcn_rcpf(1.f + ez);
        const float e = __expf(-2.f * fabsf(vh));
        float th = (1.f - e) * __builtin_amdgcn_rcpf(1.f + e);
        th = (vh < 0.f) ? -th : th;
        float a = 1.f - z;
        a = fminf(fmaxf(a, 1e-8f), 1.f - 1e-8f);
        const float bb = z * th;
        __half2 pk;
        pk.x = __float2half_rn(a);
        pk.y = __float2half_rn(bb);
        AB[(size_t)gm * H + gn] = pk;
        Aseg = a * Aseg;
        Bseg = a * Bseg + bb;
      }
      // ordered tree over the 4 lane-groups (lk): comb(first,second)
      float pa = __shfl_xor(Aseg, 16);
      float pb = __shfl_xor(Bseg, 16);
      if (lane & 16) { Bseg = Aseg * pb + Bseg; Aseg = Aseg * pa; }
      else           { Bseg = pa * Bseg + pb;   Aseg = pa * Aseg; }
      pa = __shfl_xor(Aseg, 32);
      pb = __shfl_xor(Bseg, 32);
      if (lane & 32) { Bseg = Aseg * pb + Bseg; Aseg = Aseg * pa; }
      else           { Bseg = pa * Bseg + pb;   Aseg = pa * Aseg; }
      // compose this 16-row m-block into the chunk total for column n
      Bt[n] = Aseg * Bt[n] + Bseg;
      At[n] = Aseg * At[n];
    }
  }
  if (lk == 0) {
#pragma unroll
    for (int n = 0; n < 4; ++n) {
      const int gn = n0 + wc * 64 + n * 16 + lr;
      const size_t so = (size_t)cg * H + gn;
      cA[so] = At[n];
      cB[so] = Bt[n];
    }
  }
}

// Wave-parallel exclusive scan over chunk summaries: one wave per (b,h),
// Hillis-Steele affine scan over 2 segments of 64 chunks.
__global__ __launch_bounds__(256)
void scan_summary(const float* __restrict__ cA,
                  const float* __restrict__ cB,
                  float* __restrict__ pref) {
  const int w = blockIdx.x * 4 + (threadIdx.x >> 6);  // b*H + h
  const int lane = threadIdx.x & 63;
  const int b = w >> 9, h = w & (H - 1);
  float hin = 0.f;
#pragma unroll
  for (int seg = 0; seg < 2; ++seg) {
    const int c = seg * 64 + lane;
    const size_t so = ((size_t)b * NC + c) * H + h;
    float A = cA[so], Bv = cB[so];
#pragma unroll
    for (int d = 1; d < 64; d <<= 1) {
      const float pa = __shfl_up(A, d);
      const float pb = __shfl_up(Bv, d);
      if (lane >= d) { Bv = A * pb + Bv; A = A * pa; }
    }
    float eA = __shfl_up(A, 1);
    float eB = __shfl_up(Bv, 1);
    if (lane == 0) { eA = 1.f; eB = 0.f; }
    pref[so] = eA * hin + eB;
    const float tA = __shfl(A, 63);
    const float tB = __shfl(Bv, 63);
    hin = tA * hin + tB;
  }
}

// Apply: local scan with chunk prefix; reads packed (a,b), writes f32 h.
__global__ __launch_bounds__(512)
void scan_apply(const __half2* __restrict__ AB, float* __restrict__ out,
                const float* __restrict__ pref) {
  const int blk = blockIdx.x;
  const int b = blk / NC, c = blk % NC;
  const int h = threadIdx.x;
  const size_t base = ((size_t)b * S + (size_t)c * CH) * H + h;
  float hcur = pref[((size_t)b * NC + c) * H + h];
#pragma unroll 4
  for (int t = 0; t < CH; ++t) {
    const size_t off = base + (size_t)t * H;
    const float2 f = __half22float2(AB[off]);
    hcur = f.x * hcur + f.y;
    out[off] = hcur;
  }
}

extern "C" void kernel_launch(void* const* d_in, const int* in_sizes, int n_in,
                              void* d_out, int out_size, void* d_ws, size_t ws_size,
                              hipStream_t stream) {
  const float* x  = (const float*)d_in[0];
  const float* Wz = (const float*)d_in[1];
  const float* bz = (const float*)d_in[2];
  const float* Wh = (const float*)d_in[3];
  const float* bh = (const float*)d_in[4];
  float* out = (float*)d_out;

  char* ws = (char*)d_ws;
  __half2* AB = (__half2*)ws;                      // M*H half2 = 64 MB
  bf16*  Wzb  = (bf16*)(ws + (size_t)67108864);    // H*D bf16  = 0.5 MB
  bf16*  Whb  = (bf16*)(ws + (size_t)67633152);    // H*D bf16  = 0.5 MB
  float* cA   = (float*)(ws + (size_t)68157440);   // NB*NC*H   = 1 MB
  float* cB   = (float*)(ws + (size_t)69206016);   // 1 MB
  float* pref = (float*)(ws + (size_t)70254592);   // 1 MB

  cvt_w<<<2 * H * (D / 8) / 256, 256, 0, stream>>>(Wz, Wzb, Wh, Whb);
  gemm_gates<<<(M / BM) * (H / BN), 256, 0, stream>>>(x, Wzb, Whb, bz, bh,
                                                      AB, cA, cB);
  scan_summary<<<NB * H / 4, 256, 0, stream>>>(cA, cB, pref);
  scan_apply<<<NB * NC, H, 0, stream>>>(AB, out, pref);
}